// Round 1
// baseline (87.880 us; speedup 1.0000x reference)
//
#include <hip/hip_runtime.h>

#define VOCAB 100000
#define D 300
#define NS 256
#define NA 256
#define W 8
#define NROWS 2048   // 256*8
#define KP 304       // D padded to multiple of 16
#define EPS 1e-8
#define BLK 64
#define BK 16

// ---------------- gather + norms + none flags ----------------
__global__ __launch_bounds__(64) void k_gather(const float* __restrict__ emb,
                                               const int* __restrict__ sen_cats,
                                               const int* __restrict__ ann_cats,
                                               const int* __restrict__ none_idx,
                                               float* __restrict__ Arow,
                                               float* __restrict__ Brow,
                                               double* __restrict__ snorm,
                                               double* __restrict__ anorm,
                                               int* __restrict__ sflag) {
    int rid = blockIdx.x;
    bool isSen = rid < NROWS;
    int r = isSen ? rid : rid - NROWS;
    int cat = isSen ? sen_cats[r] : ann_cats[r];
    const float4* src = reinterpret_cast<const float4*>(emb + (size_t)cat * D);
    float4* dst = reinterpret_cast<float4*>((isSen ? Arow : Brow) + (size_t)r * KP);
    int tid = threadIdx.x;
    double acc = 0.0;
    for (int i = tid; i < 75; i += 64) {        // 300 floats = 75 float4
        float4 v = src[i];
        dst[i] = v;
        acc += (double)v.x * v.x + (double)v.y * v.y +
               (double)v.z * v.z + (double)v.w * v.w;
    }
    if (tid == 0) dst[75] = make_float4(0.f, 0.f, 0.f, 0.f);  // zero the K-pad
    // wave (=block) reduce
    for (int off = 32; off > 0; off >>= 1) acc += __shfl_down(acc, off, 64);
    if (tid == 0) {
        double n = sqrt(acc);
        if (isSen) {
            snorm[r] = n;
            sflag[r] = (cat == none_idx[0]) ? 1 : 0;
        } else {
            anorm[r] = n;
        }
    }
}

// ---------------- sen_wd_emb = sum over w of sen_e ----------------
__global__ __launch_bounds__(128) void k_sumemb(const float* __restrict__ Arow,
                                                float* __restrict__ out2) {
    int s = blockIdx.x;
    for (int d = threadIdx.x; d < D; d += 128) {
        float sum = 0.f;
#pragma unroll
        for (int w = 0; w < W; ++w)
            sum += Arow[(size_t)(s * W + w) * KP + d];
        out2[s * D + d] = sum;
    }
}

// ---------------- main: dots + cosine + order-dependent fold ----------------
__global__ __launch_bounds__(256) void k_main(const float* __restrict__ Arow,
                                              const float* __restrict__ Brow,
                                              const double* __restrict__ snorm,
                                              const double* __restrict__ anorm,
                                              const int* __restrict__ sflag,
                                              float* __restrict__ out) {
    __shared__ union {
        struct {
            float As[BK][BLK + 4];  // k-major, padded: [16][68]
            float Bs[BK][BLK + 4];
        } t;
        double Cs[64][66];          // cos tile for the fold phase
    } sm;

    int tid = threadIdx.x;
    int ty = tid >> 4, tx = tid & 15;
    int by = blockIdx.y, bx = blockIdx.x;

    double acc[4][4] = {};

    int lrow = tid >> 2, lkq = tid & 3;  // 64 rows x 4 k-quads of float4
    const float* Ab = Arow + (size_t)(by * BLK + lrow) * KP + lkq * 4;
    const float* Bb = Brow + (size_t)(bx * BLK + lrow) * KP + lkq * 4;

    for (int k0 = 0; k0 < KP; k0 += BK) {
        float4 va = *reinterpret_cast<const float4*>(Ab + k0);
        float4 vb = *reinterpret_cast<const float4*>(Bb + k0);
        __syncthreads();  // previous iter's reads done before overwrite
        sm.t.As[lkq * 4 + 0][lrow] = va.x;
        sm.t.As[lkq * 4 + 1][lrow] = va.y;
        sm.t.As[lkq * 4 + 2][lrow] = va.z;
        sm.t.As[lkq * 4 + 3][lrow] = va.w;
        sm.t.Bs[lkq * 4 + 0][lrow] = vb.x;
        sm.t.Bs[lkq * 4 + 1][lrow] = vb.y;
        sm.t.Bs[lkq * 4 + 2][lrow] = vb.z;
        sm.t.Bs[lkq * 4 + 3][lrow] = vb.w;
        __syncthreads();
#pragma unroll
        for (int kk = 0; kk < BK; ++kk) {
            float4 af = *reinterpret_cast<const float4*>(&sm.t.As[kk][ty * 4]);
            float4 bf = *reinterpret_cast<const float4*>(&sm.t.Bs[kk][tx * 4]);
            double a0 = af.x, a1 = af.y, a2 = af.z, a3 = af.w;
            double b0 = bf.x, b1 = bf.y, b2 = bf.z, b3 = bf.w;
            acc[0][0] = fma(a0, b0, acc[0][0]);
            acc[0][1] = fma(a0, b1, acc[0][1]);
            acc[0][2] = fma(a0, b2, acc[0][2]);
            acc[0][3] = fma(a0, b3, acc[0][3]);
            acc[1][0] = fma(a1, b0, acc[1][0]);
            acc[1][1] = fma(a1, b1, acc[1][1]);
            acc[1][2] = fma(a1, b2, acc[1][2]);
            acc[1][3] = fma(a1, b3, acc[1][3]);
            acc[2][0] = fma(a2, b0, acc[2][0]);
            acc[2][1] = fma(a2, b1, acc[2][1]);
            acc[2][2] = fma(a2, b2, acc[2][2]);
            acc[2][3] = fma(a2, b3, acc[2][3]);
            acc[3][0] = fma(a3, b0, acc[3][0]);
            acc[3][1] = fma(a3, b1, acc[3][1]);
            acc[3][2] = fma(a3, b2, acc[3][2]);
            acc[3][3] = fma(a3, b3, acc[3][3]);
        }
    }

    __syncthreads();  // done with As/Bs, reuse LDS as Cs
#pragma unroll
    for (int i = 0; i < 4; ++i) {
        int r = ty * 4 + i;
        int sw = by * BLK + r;
        double ns = snorm[sw];
        int fl = sflag[sw];
#pragma unroll
        for (int j = 0; j < 4; ++j) {
            int c = tx * 4 + j;
            int aw = bx * BLK + c;
            double denom = fmax(ns * anorm[aw], EPS);
            double cv = fl ? 0.0 : acc[i][j] / denom;
            sm.Cs[r][c] = cv;
        }
    }
    __syncthreads();

    if (tid < 64) {
        int sl = tid >> 3, al = tid & 7;
        double cur = 0.0;
#pragma unroll
        for (int w = 0; w < W; ++w) {
#pragma unroll
            for (int v = 0; v < W; ++v) {
                double sv = sm.Cs[sl * 8 + w][al * 8 + v];
                cur = (sv >= cur || sv < 0.0) ? sv : cur;
            }
        }
        out[(by * 8 + sl) * NA + (bx * 8 + al)] = (float)cur;
    }
}

extern "C" void kernel_launch(void* const* d_in, const int* in_sizes, int n_in,
                              void* d_out, int out_size, void* d_ws, size_t ws_size,
                              hipStream_t stream) {
    const float* emb = (const float*)d_in[0];
    const int* sen = (const int*)d_in[1];
    const int* ann = (const int*)d_in[2];
    const int* none = (const int*)d_in[3];
    float* out = (float*)d_out;

    char* ws = (char*)d_ws;
    float* Arow = (float*)(ws + 0);                  // 2048*304*4 = 2,490,368
    float* Brow = (float*)(ws + 2490368);            // 2,490,368
    double* snorm = (double*)(ws + 4980736);         // 16,384
    double* anorm = (double*)(ws + 4997120);         // 16,384
    int* sflag = (int*)(ws + 5013504);               // 8,192

    hipLaunchKernelGGL(k_gather, dim3(4096), dim3(64), 0, stream,
                       emb, sen, ann, none, Arow, Brow, snorm, anorm, sflag);
    hipLaunchKernelGGL(k_sumemb, dim3(256), dim3(128), 0, stream,
                       Arow, out + NS * NA);
    hipLaunchKernelGGL(k_main, dim3(32, 32), dim3(256), 0, stream,
                       Arow, Brow, snorm, anorm, sflag, out);
}

// Round 2
// 77.734 us; speedup vs baseline: 1.1305x; 1.1305x over previous
//
#include <hip/hip_runtime.h>

#define VOCAB 100000
#define D 300
#define NS 256
#define NA 256
#define W 8
#define NROWS 2048   // 256*8
#define KP 304       // D padded to multiple of 16
#define BM 128       // tile edge (words)
#define BK 16
#define NSTAGE (KP / BK)   // 19
#define LDR (BM + 2)       // LDS row stride in doubles (16B-aligned rows)

// ---------------- gather + reciprocal norms + none flags ----------------
__global__ __launch_bounds__(64) void k_gather(const float* __restrict__ emb,
                                               const int* __restrict__ sen_cats,
                                               const int* __restrict__ ann_cats,
                                               const int* __restrict__ none_idx,
                                               float* __restrict__ Arow,
                                               float* __restrict__ Brow,
                                               double* __restrict__ rsn,
                                               double* __restrict__ ran,
                                               int* __restrict__ sflag) {
    int rid = blockIdx.x;
    bool isSen = rid < NROWS;
    int r = isSen ? rid : rid - NROWS;
    int cat = isSen ? sen_cats[r] : ann_cats[r];
    const float4* src = reinterpret_cast<const float4*>(emb + (size_t)cat * D);
    float4* dst = reinterpret_cast<float4*>((isSen ? Arow : Brow) + (size_t)r * KP);
    int tid = threadIdx.x;
    double acc = 0.0;
    for (int i = tid; i < 75; i += 64) {        // 300 floats = 75 float4
        float4 v = src[i];
        dst[i] = v;
        acc += (double)v.x * v.x + (double)v.y * v.y +
               (double)v.z * v.z + (double)v.w * v.w;
    }
    if (tid == 0) dst[75] = make_float4(0.f, 0.f, 0.f, 0.f);  // zero K-pad
    for (int off = 32; off > 0; off >>= 1) acc += __shfl_down(acc, off, 64);
    if (tid == 0) {
        double rn = 1.0 / sqrt(acc);   // norms ~17, eps clamp unreachable
        if (isSen) {
            rsn[r] = rn;
            sflag[r] = (cat == none_idx[0]) ? 1 : 0;
        } else {
            ran[r] = rn;
        }
    }
}

// ---------------- sen_wd_emb = sum over w of sen_e ----------------
__global__ __launch_bounds__(128) void k_sumemb(const float* __restrict__ Arow,
                                                float* __restrict__ out2) {
    int s = blockIdx.x;
    for (int d = threadIdx.x; d < D; d += 128) {
        float sum = 0.f;
#pragma unroll
        for (int w = 0; w < W; ++w)
            sum += Arow[(size_t)(s * W + w) * KP + d];
        out2[s * D + d] = sum;
    }
}

// ---------------- main: one (s,a) pair per thread, in-register fold ----------------
__global__ __launch_bounds__(256, 1) void k_main(const float* __restrict__ Arow,
                                                 const float* __restrict__ Brow,
                                                 const double* __restrict__ rsn,
                                                 const double* __restrict__ ran,
                                                 const int* __restrict__ sflag,
                                                 float* __restrict__ out) {
    __shared__ double As[BK][LDR];   // k-major, doubles (cvt once at staging)
    __shared__ double Bs[BK][LDR];

    int tid = threadIdx.x;
    int ty = tid >> 4, tx = tid & 15;          // (s,a) pair within tile
    int by = blockIdx.y, bx = blockIdx.x;

    // staging map: q = k-quad (0..3), r0 = tile row (0..63); rows r0 and r0+64
    int q = tid & 3, r0 = tid >> 2;
    int kb = q * 4;
    const float* Ag = Arow + (size_t)(by * BM + r0) * KP + q * 4;
    const float* Bg = Brow + (size_t)(bx * BM + r0) * KP + q * 4;

    // prologue: load stage 0
    float4 pa0 = *reinterpret_cast<const float4*>(Ag);
    float4 pa1 = *reinterpret_cast<const float4*>(Ag + 64 * KP);
    float4 pb0 = *reinterpret_cast<const float4*>(Bg);
    float4 pb1 = *reinterpret_cast<const float4*>(Bg + 64 * KP);

    double acc[W][W] = {};

    for (int st = 0; st < NSTAGE; ++st) {
        __syncthreads();   // previous iter's LDS reads complete
        As[kb + 0][r0] = (double)pa0.x;
        As[kb + 1][r0] = (double)pa0.y;
        As[kb + 2][r0] = (double)pa0.z;
        As[kb + 3][r0] = (double)pa0.w;
        As[kb + 0][r0 + 64] = (double)pa1.x;
        As[kb + 1][r0 + 64] = (double)pa1.y;
        As[kb + 2][r0 + 64] = (double)pa1.z;
        As[kb + 3][r0 + 64] = (double)pa1.w;
        Bs[kb + 0][r0] = (double)pb0.x;
        Bs[kb + 1][r0] = (double)pb0.y;
        Bs[kb + 2][r0] = (double)pb0.z;
        Bs[kb + 3][r0] = (double)pb0.w;
        Bs[kb + 0][r0 + 64] = (double)pb1.x;
        Bs[kb + 1][r0 + 64] = (double)pb1.y;
        Bs[kb + 2][r0 + 64] = (double)pb1.z;
        Bs[kb + 3][r0 + 64] = (double)pb1.w;
        // prefetch next stage into regs (hidden under compute)
        if (st + 1 < NSTAGE) {
            const float* Ag2 = Ag + (st + 1) * BK;
            const float* Bg2 = Bg + (st + 1) * BK;
            pa0 = *reinterpret_cast<const float4*>(Ag2);
            pa1 = *reinterpret_cast<const float4*>(Ag2 + 64 * KP);
            pb0 = *reinterpret_cast<const float4*>(Bg2);
            pb1 = *reinterpret_cast<const float4*>(Bg2 + 64 * KP);
        }
        __syncthreads();
#pragma unroll
        for (int kk = 0; kk < BK; ++kk) {
            const double2* ap = reinterpret_cast<const double2*>(&As[kk][ty * 8]);
            const double2* bp = reinterpret_cast<const double2*>(&Bs[kk][tx * 8]);
            double2 a0 = ap[0], a1 = ap[1], a2 = ap[2], a3 = ap[3];
            double2 b0 = bp[0], b1 = bp[1], b2 = bp[2], b3 = bp[3];
            double av[W] = {a0.x, a0.y, a1.x, a1.y, a2.x, a2.y, a3.x, a3.y};
            double bv[W] = {b0.x, b0.y, b1.x, b1.y, b2.x, b2.y, b3.x, b3.y};
#pragma unroll
            for (int w = 0; w < W; ++w)
#pragma unroll
                for (int v = 0; v < W; ++v)
                    acc[w][v] = fma(av[w], bv[v], acc[w][v]);
        }
    }

    // epilogue: cosine + order-dependent fold, all in registers
    int s = by * 16 + ty;
    int a = bx * 16 + tx;
    double rs[W], ra[W];
    int fl[W];
#pragma unroll
    for (int w = 0; w < W; ++w) {
        rs[w] = rsn[s * W + w];
        fl[w] = sflag[s * W + w];
    }
#pragma unroll
    for (int v = 0; v < W; ++v) ra[v] = ran[a * W + v];

    double cur = 0.0;
#pragma unroll
    for (int w = 0; w < W; ++w) {
        double rw = rs[w];
        int f = fl[w];
#pragma unroll
        for (int v = 0; v < W; ++v) {
            double cv = f ? 0.0 : acc[w][v] * (rw * ra[v]);
            cur = (cv >= cur || cv < 0.0) ? cv : cur;
        }
    }
    out[s * NA + a] = (float)cur;
}

extern "C" void kernel_launch(void* const* d_in, const int* in_sizes, int n_in,
                              void* d_out, int out_size, void* d_ws, size_t ws_size,
                              hipStream_t stream) {
    const float* emb = (const float*)d_in[0];
    const int* sen = (const int*)d_in[1];
    const int* ann = (const int*)d_in[2];
    const int* none = (const int*)d_in[3];
    float* out = (float*)d_out;

    char* ws = (char*)d_ws;
    float* Arow = (float*)(ws + 0);                  // 2048*304*4 = 2,490,368
    float* Brow = (float*)(ws + 2490368);            // 2,490,368
    double* rsn = (double*)(ws + 4980736);           // 16,384
    double* ran = (double*)(ws + 4997120);           // 16,384
    int* sflag = (int*)(ws + 5013504);               // 8,192

    hipLaunchKernelGGL(k_gather, dim3(4096), dim3(64), 0, stream,
                       emb, sen, ann, none, Arow, Brow, rsn, ran, sflag);
    hipLaunchKernelGGL(k_sumemb, dim3(256), dim3(128), 0, stream,
                       Arow, out + NS * NA);
    hipLaunchKernelGGL(k_main, dim3(16, 16), dim3(256), 0, stream,
                       Arow, Brow, rsn, ran, sflag, out);
}

// Round 3
// 56.569 us; speedup vs baseline: 1.5535x; 1.3741x over previous
//
#include <hip/hip_runtime.h>

#define VOCAB 100000
#define D 300
#define NS 256
#define NA 256
#define W 8
#define NROWS 2048   // 256*8
#define KP 304       // D padded to multiple of 16
#define BK 16
#define NSTAGE (KP / BK)   // 19
#define LDR 132            // LDS row stride (floats), 16B-aligned rows

// ---------------- gather + reciprocal norms + none flags ----------------
__global__ __launch_bounds__(64) void k_gather(const float* __restrict__ emb,
                                               const int* __restrict__ sen_cats,
                                               const int* __restrict__ ann_cats,
                                               const int* __restrict__ none_idx,
                                               float* __restrict__ Arow,
                                               float* __restrict__ Brow,
                                               float* __restrict__ rsn,
                                               float* __restrict__ ran,
                                               int* __restrict__ sflag) {
    int rid = blockIdx.x;
    bool isSen = rid < NROWS;
    int r = isSen ? rid : rid - NROWS;
    int cat = isSen ? sen_cats[r] : ann_cats[r];
    const float4* src = reinterpret_cast<const float4*>(emb + (size_t)cat * D);
    float4* dst = reinterpret_cast<float4*>((isSen ? Arow : Brow) + (size_t)r * KP);
    int tid = threadIdx.x;
    double acc = 0.0;
    for (int i = tid; i < 75; i += 64) {        // 300 floats = 75 float4
        float4 v = src[i];
        dst[i] = v;
        acc += (double)v.x * v.x + (double)v.y * v.y +
               (double)v.z * v.z + (double)v.w * v.w;
    }
    if (tid == 0) dst[75] = make_float4(0.f, 0.f, 0.f, 0.f);  // zero K-pad
    for (int off = 32; off > 0; off >>= 1) acc += __shfl_down(acc, off, 64);
    if (tid == 0) {
        float rn = (float)(1.0 / sqrt(acc));   // norms ~17, eps clamp unreachable
        if (isSen) {
            rsn[r] = rn;
            sflag[r] = (cat == none_idx[0]) ? 1 : 0;
        } else {
            ran[r] = rn;
        }
    }
}

// ---------------- sen_wd_emb = sum over w of sen_e ----------------
__global__ __launch_bounds__(128) void k_sumemb(const float* __restrict__ Arow,
                                                float* __restrict__ out2) {
    int s = blockIdx.x;
    for (int d = threadIdx.x; d < D; d += 128) {
        float sum = 0.f;
#pragma unroll
        for (int w = 0; w < W; ++w)
            sum += Arow[(size_t)(s * W + w) * KP + d];
        out2[s * D + d] = sum;
    }
}

// ---------------- main: fp32, wave-quadrant 8x8 lanes, dbuf LDS ----------------
__global__ __launch_bounds__(256, 1) void k_main(const float* __restrict__ Arow,
                                                 const float* __restrict__ Brow,
                                                 const float* __restrict__ rsn,
                                                 const float* __restrict__ ran,
                                                 const int* __restrict__ sflag,
                                                 float* __restrict__ out) {
    __shared__ float As[2][BK][LDR];
    __shared__ float Bs[2][BK][LDR];

    int tid = threadIdx.x;
    int wv = tid >> 6, lane = tid & 63;
    int qy = wv >> 1, qx = wv & 1;          // wave's 64x64 quadrant
    int ty8 = lane >> 3, tx8 = lane & 7;    // 8x8 lane grid inside quadrant
    int sLoc = qy * 64 + ty8 * 8;           // word-column base in As rows
    int aLoc = qx * 64 + tx8 * 8;
    int by = blockIdx.y, bx = blockIdx.x;

    // staging map: q = k-quad (0..3), r0 = tile row (0..63); rows r0, r0+64
    int q = tid & 3, r0 = tid >> 2;
    int kb = q * 4;
    const float* Ag = Arow + (size_t)(by * 128 + r0) * KP + q * 4;
    const float* Bg = Brow + (size_t)(bx * 128 + r0) * KP + q * 4;

    // prologue: stage 0 into buffer 0
    float4 pa0 = *reinterpret_cast<const float4*>(Ag);
    float4 pa1 = *reinterpret_cast<const float4*>(Ag + 64 * KP);
    float4 pb0 = *reinterpret_cast<const float4*>(Bg);
    float4 pb1 = *reinterpret_cast<const float4*>(Bg + 64 * KP);
    {
        float av0[4] = {pa0.x, pa0.y, pa0.z, pa0.w};
        float av1[4] = {pa1.x, pa1.y, pa1.z, pa1.w};
        float bv0[4] = {pb0.x, pb0.y, pb0.z, pb0.w};
        float bv1[4] = {pb1.x, pb1.y, pb1.z, pb1.w};
#pragma unroll
        for (int i = 0; i < 4; ++i) {
            As[0][kb + i][r0] = av0[i];
            As[0][kb + i][r0 + 64] = av1[i];
            Bs[0][kb + i][r0] = bv0[i];
            Bs[0][kb + i][r0 + 64] = bv1[i];
        }
    }

    float acc[W][W] = {};

    for (int st = 0; st < NSTAGE; ++st) {
        int cur = st & 1;
        __syncthreads();   // stage st's LDS writes visible; prev reads done
        // issue next-stage global loads (latency hidden under compute)
        if (st + 1 < NSTAGE) {
            const float* Ag2 = Ag + (st + 1) * BK;
            const float* Bg2 = Bg + (st + 1) * BK;
            pa0 = *reinterpret_cast<const float4*>(Ag2);
            pa1 = *reinterpret_cast<const float4*>(Ag2 + 64 * KP);
            pb0 = *reinterpret_cast<const float4*>(Bg2);
            pb1 = *reinterpret_cast<const float4*>(Bg2 + 64 * KP);
        }
#pragma unroll
        for (int kk = 0; kk < BK; ++kk) {
            float4 a0 = *reinterpret_cast<const float4*>(&As[cur][kk][sLoc]);
            float4 a1 = *reinterpret_cast<const float4*>(&As[cur][kk][sLoc + 4]);
            float4 b0 = *reinterpret_cast<const float4*>(&Bs[cur][kk][aLoc]);
            float4 b1 = *reinterpret_cast<const float4*>(&Bs[cur][kk][aLoc + 4]);
            float av[W] = {a0.x, a0.y, a0.z, a0.w, a1.x, a1.y, a1.z, a1.w};
            float bv[W] = {b0.x, b0.y, b0.z, b0.w, b1.x, b1.y, b1.z, b1.w};
#pragma unroll
            for (int w = 0; w < W; ++w)
#pragma unroll
                for (int v = 0; v < W; ++v)
                    acc[w][v] = __builtin_fmaf(av[w], bv[v], acc[w][v]);
        }
        // write stage st+1 into the other buffer (overlaps with compute above)
        if (st + 1 < NSTAGE) {
            int nxt = cur ^ 1;
            float av0[4] = {pa0.x, pa0.y, pa0.z, pa0.w};
            float av1[4] = {pa1.x, pa1.y, pa1.z, pa1.w};
            float bv0[4] = {pb0.x, pb0.y, pb0.z, pb0.w};
            float bv1[4] = {pb1.x, pb1.y, pb1.z, pb1.w};
#pragma unroll
            for (int i = 0; i < 4; ++i) {
                As[nxt][kb + i][r0] = av0[i];
                As[nxt][kb + i][r0 + 64] = av1[i];
                Bs[nxt][kb + i][r0] = bv0[i];
                Bs[nxt][kb + i][r0 + 64] = bv1[i];
            }
        }
    }

    // epilogue: cosine + order-dependent fold, all in registers (fp32)
    int s = by * 16 + qy * 8 + ty8;
    int a = bx * 16 + qx * 8 + tx8;
    float rs[W], ra[W];
    int fl[W];
#pragma unroll
    for (int w = 0; w < W; ++w) {
        rs[w] = rsn[s * W + w];
        fl[w] = sflag[s * W + w];
    }
#pragma unroll
    for (int v = 0; v < W; ++v) ra[v] = ran[a * W + v];

    float cur = 0.f;
#pragma unroll
    for (int w = 0; w < W; ++w) {
        float rw = rs[w];
        int f = fl[w];
#pragma unroll
        for (int v = 0; v < W; ++v) {
            float cv = f ? 0.f : acc[w][v] * (rw * ra[v]);
            cur = (cv >= cur || cv < 0.f) ? cv : cur;
        }
    }
    out[s * NA + a] = cur;
}

extern "C" void kernel_launch(void* const* d_in, const int* in_sizes, int n_in,
                              void* d_out, int out_size, void* d_ws, size_t ws_size,
                              hipStream_t stream) {
    const float* emb = (const float*)d_in[0];
    const int* sen = (const int*)d_in[1];
    const int* ann = (const int*)d_in[2];
    const int* none = (const int*)d_in[3];
    float* out = (float*)d_out;

    char* ws = (char*)d_ws;
    float* Arow = (float*)(ws + 0);                  // 2048*304*4 = 2,490,368
    float* Brow = (float*)(ws + 2490368);            // 2,490,368
    float* rsn = (float*)(ws + 4980736);             // 8,192
    float* ran = (float*)(ws + 4988928);             // 8,192
    int* sflag = (int*)(ws + 4997120);               // 8,192

    hipLaunchKernelGGL(k_gather, dim3(4096), dim3(64), 0, stream,
                       emb, sen, ann, none, Arow, Brow, rsn, ran, sflag);
    hipLaunchKernelGGL(k_sumemb, dim3(256), dim3(128), 0, stream,
                       Arow, out + NS * NA);
    hipLaunchKernelGGL(k_main, dim3(16, 16), dim3(256), 0, stream,
                       Arow, Brow, rsn, ran, sflag, out);
}